// Round 13
// baseline (477.304 us; speedup 1.0000x reference)
//
#include <hip/hip_runtime.h>

typedef unsigned short u16;
typedef __bf16 bf16x8 __attribute__((ext_vector_type(8)));
typedef u16 u16x8 __attribute__((ext_vector_type(8)));
typedef u16 u16x4 __attribute__((ext_vector_type(4)));
typedef float f32x4 __attribute__((ext_vector_type(4)));

#define MFMA16(a, b, c) __builtin_amdgcn_mfma_f32_16x16x32_bf16((a), (b), (c), 0, 0, 0)

__device__ __forceinline__ void async16(const u16* g, u16* l) {
  __builtin_amdgcn_global_load_lds(
      (__attribute__((address_space(1))) void*)(void*)(g),
      (__attribute__((address_space(3))) void*)(void*)(l), 16, 0, 0);
}

__device__ __forceinline__ float bf2f(u16 b) {
  union { unsigned u; float f; } v;
  v.u = ((unsigned)b) << 16;
  return v.f;
}
__device__ __forceinline__ u16 f2bf(float f) {
  union { float f; unsigned u; } v;
  v.f = f;
  unsigned u = v.u;
  return (u16)((u + 0x7FFFu + ((u >> 16) & 1u)) >> 16);
}

// ---------------- input convert: fp32 -> bf16, 8 elems/thread ----------------
__global__ __launch_bounds__(256) void convert_k(const float* __restrict__ in,
                                                 u16* __restrict__ out, int n8) {
  const int stride = gridDim.x * 256;
  for (int i = blockIdx.x * 256 + threadIdx.x; i < n8; i += stride) {
    const float* fp = in + (size_t)i * 8;
    float4 a = *(const float4*)fp, b = *(const float4*)(fp + 4);
    u16x8 o;
    o[0] = f2bf(a.x); o[1] = f2bf(a.y); o[2] = f2bf(a.z); o[3] = f2bf(a.w);
    o[4] = f2bf(b.x); o[5] = f2bf(b.y); o[6] = f2bf(b.z); o[7] = f2bf(b.w);
    *(u16x8*)&out[(size_t)i * 8] = o;
  }
}

// ---------------- weight transpose+convert: W[K][N] fp32 -> Wt[N][K] bf16 ----------------
__global__ __launch_bounds__(256) void transpose_cvt_k(const float* __restrict__ W,
                                                       u16* __restrict__ Wt, int K, int N) {
  __shared__ __align__(16) u16 tile[64 * 72];
  const int t = threadIdx.x;
  const int n0 = blockIdx.x * 64, k0 = blockIdx.y * 64;
#pragma unroll
  for (int i = 0; i < 2; ++i) {
    int flat = t + i * 256;
    int r = flat >> 3, c8 = (flat & 7) * 8;
    const float* p = W + (size_t)(k0 + r) * N + n0 + c8;
    float4 a = *(const float4*)p, b = *(const float4*)(p + 4);
    u16x8 v;
    v[0] = f2bf(a.x); v[1] = f2bf(a.y); v[2] = f2bf(a.z); v[3] = f2bf(a.w);
    v[4] = f2bf(b.x); v[5] = f2bf(b.y); v[6] = f2bf(b.z); v[7] = f2bf(b.w);
#pragma unroll
    for (int j = 0; j < 8; ++j) tile[r * 72 + c8 + j] = v[j];
  }
  __syncthreads();
#pragma unroll
  for (int i = 0; i < 2; ++i) {
    int flat = t + i * 256;
    int r = flat >> 3, c8 = (flat & 7) * 8;
    u16x8 v;
#pragma unroll
    for (int j = 0; j < 8; ++j) v[j] = tile[(c8 + j) * 72 + r];
    *(u16x8*)&Wt[(size_t)(n0 + r) * K + k0 + c8] = v;
  }
}

// ---------------- RoPE cos/sin table: [2048][64] f32 ----------------
__global__ __launch_bounds__(256) void rope_table_k(float* __restrict__ cosT,
                                                    float* __restrict__ sinT) {
  int idx = blockIdx.x * 256 + threadIdx.x;  // t*64 + i
  int tp = idx >> 6, i = idx & 63;
  float invf = expf(-(float)i * (9.210340371976184f / 64.0f));  // 10000^{-i/64}
  float ang = (float)tp * invf;
  cosT[idx] = cosf(ang);
  sinT[idx] = sinf(ang);
}

// ---------------- RoPE apply (in place), optional scale fold ----------------
__global__ __launch_bounds__(256) void rope_apply_k(u16* __restrict__ base,
                                                    const float* __restrict__ cosT,
                                                    const float* __restrict__ sinT,
                                                    int rowStride, int nhMask, int rowShift,
                                                    float scale) {
  int idx = blockIdx.x * 256 + threadIdx.x;
  int i4 = idx & 15;
  int hh = (idx >> 4) & nhMask;
  int row = idx >> rowShift;
  int tp = row & 2047;
  int i = i4 * 4;
  u16* p = base + (size_t)row * rowStride + hh * 128;
  u16x4 a = *(u16x4*)&p[i];
  u16x4 b = *(u16x4*)&p[i + 64];
  float4 c = *(const float4*)&cosT[tp * 64 + i];
  float4 s = *(const float4*)&sinT[tp * 64 + i];
  float cc[4] = {c.x, c.y, c.z, c.w}, ss[4] = {s.x, s.y, s.z, s.w};
  u16x4 oa, ob;
#pragma unroll
  for (int j = 0; j < 4; ++j) {
    float x1 = bf2f(a[j]), x2 = bf2f(b[j]);
    oa[j] = f2bf((x1 * cc[j] - x2 * ss[j]) * scale);
    ob[j] = f2bf((x2 * cc[j] + x1 * ss[j]) * scale);
  }
  *(u16x4*)&p[i] = oa;
  *(u16x4*)&p[i + 64] = ob;
}

// ---------------- 8-phase 256x256 GEMM: C[M][N] = A[M][K] @ Bt[N][K]^T ----------------
// T2 chunk-XOR swizzle + T3 8-phase + T4 counted vmcnt + T5 setprio (catalog §5.5).
// 8 waves (2M x 4N), per-wave C = 128x64 (acc[8][4]). LDS = 2 dbuf x (A 32K + B 32K) = 128 KB.
// Iteration = 2 K-tiles (BK=64 each): ph0-3 compute dbuf0 quadrants + stage tile(2i+1)->dbuf1;
// ph4-7 compute dbuf1 + stage tile(2i+2)->dbuf0. Re-stage of any half is issued >=1 barrier
// after its last ds_read completes (race-free by construction). vmcnt(2) gates each tile.
template <bool F32OUT>
__global__ __launch_bounds__(512, 1) void gemm8p(const u16* __restrict__ A,
                                                 const u16* __restrict__ Bt,
                                                 void* __restrict__ C, int M, int N, int K) {
  __shared__ __align__(16) u16 As[2][256 * 64];
  __shared__ __align__(16) u16 Bs[2][256 * 64];
  const int t = threadIdx.x, l = t & 63, w = t >> 6;
  const int lr = l & 15, lg = l >> 4;
  const int wm = w >> 2, wn = w & 3;
  const int nbx = gridDim.x;
  const int lin = blockIdx.y * nbx + blockIdx.x;
  const int cpx = (nbx * gridDim.y) >> 3;  // grids are %8==0 (384 / 256 blocks)
  const int sl = (lin & 7) * cpx + (lin >> 3);
  const size_t m0 = (size_t)(sl / nbx) * 256, n0 = (size_t)(sl % nbx) * 256;
  const int sr = t >> 3, sc = t & 7;  // staging row/chunk for this thread

  // stage one 16KB half-tile: hk 0/1 = A-op half h, 2/3 = B-op half h; dest dbuf d.
  // Linear LDS dest (gload_lds rule #21); source chunk pre-swizzled (c ^ (r&7)).
  auto stage = [&](int hk, int kt, int d) {
    const u16* X = (hk < 2) ? A : Bt;
    const size_t x0 = (hk < 2) ? m0 : n0;
    u16* Xs = (hk < 2) ? &As[d][0] : &Bs[d][0];
    const int h = hk & 1;
#pragma unroll
    for (int j = 0; j < 2; ++j) {
      int r = sr + j * 64;  // 0..127 within half
      async16(&X[(x0 + h * 128 + r) * K + kt * 64 + ((sc ^ (r & 7)) * 8)],
              &Xs[h * 8192 + (j * 512 + t) * 8]);
    }
  };

  f32x4 acc[8][4] = {};
  const int NIT = K >> 7;  // K/128 iterations of 2 K-tiles
  // prologue: K-tile 0 -> dbuf0 (8 loads)
#pragma unroll
  for (int hk = 0; hk < 4; ++hk) stage(hk, 0, 0);

  for (int it = 0; it < NIT; ++it) {
    const int ktB = 2 * it + 1, ktN = 2 * it + 2;
    const bool last = (it + 1 == NIT);
#pragma unroll
    for (int p = 0; p < 8; ++p) {
      const int d = p >> 2, q = p & 3, miH = q >> 1, niH = q & 1;
      // ---- staging issue (before any wait; overwrites only barrier-freed regions) ----
      if (p < 4) stage(p, ktB, 1);
      else if (!last) stage(p - 4, ktN, 0);
      if (q == 0) {  // gate the tile this half-iteration reads
        if (p == 4 && last) { asm volatile("s_waitcnt vmcnt(0)" ::: "memory"); }
        else                { asm volatile("s_waitcnt vmcnt(2)" ::: "memory"); }
        __builtin_amdgcn_s_barrier();
      }
      // ---- ds reads for quadrant q (12 x b128), swizzled ----
      bf16x8 a[4][2], b[2][2];
#pragma unroll
      for (int m2 = 0; m2 < 4; ++m2)
#pragma unroll
        for (int ks = 0; ks < 2; ++ks)
          a[m2][ks] = *(const bf16x8*)&As[d][(wm * 128 + (miH * 4 + m2) * 16 + lr) * 64 +
                                            (((ks * 4 + lg) ^ (lr & 7)) << 3)];
#pragma unroll
      for (int n2 = 0; n2 < 2; ++n2)
#pragma unroll
        for (int ks = 0; ks < 2; ++ks)
          b[n2][ks] = *(const bf16x8*)&Bs[d][(wn * 64 + (niH * 2 + n2) * 16 + lr) * 64 +
                                            (((ks * 4 + lg) ^ (lr & 7)) << 3)];
      if (q != 0) __builtin_amdgcn_s_barrier();
      __builtin_amdgcn_s_setprio(1);
#pragma unroll
      for (int m2 = 0; m2 < 4; ++m2)
#pragma unroll
        for (int n2 = 0; n2 < 2; ++n2)
#pragma unroll
          for (int ks = 0; ks < 2; ++ks)
            acc[miH * 4 + m2][niH * 2 + n2] =
                MFMA16(a[m2][ks], b[n2][ks], acc[miH * 4 + m2][niH * 2 + n2]);
      __builtin_amdgcn_s_setprio(0);
      __builtin_amdgcn_s_barrier();
    }
  }
#pragma unroll
  for (int mi = 0; mi < 8; ++mi)
#pragma unroll
    for (int ni = 0; ni < 4; ++ni)
#pragma unroll
      for (int r = 0; r < 4; ++r) {
        size_t row = m0 + wm * 128 + mi * 16 + lg * 4 + r;
        size_t col = n0 + wn * 64 + ni * 16 + lr;
        if constexpr (F32OUT)
          ((float*)C)[row * N + col] = acc[mi][ni][r];
        else
          ((u16*)C)[row * N + col] = f2bf(acc[mi][ni][r]);
      }
}

// ---------------- causal GQA flash attention (8-wave, QBLK=128, 16x16 MFMA, 2-phase) ----------------
// Round-8/12 configuration (best measured ~190-195 us). P = exp(S-8), row-sum via MFMA vs ones.
__global__ __launch_bounds__(512, 4) void attn_k(const u16* __restrict__ QKV,
                                                 u16* __restrict__ O) {
  constexpr int T = 2048, CS = 3072, OC = 2048;
  __shared__ __align__(16) u16 Ks[2][64 * 128];
  __shared__ __align__(16) u16 Vt[128 * 72];
  __shared__ __align__(16) u16 Pl[128 * 72];
  const int t = threadIdx.x, l = t & 63, w = t >> 6, lr = l & 15, lg = l >> 4;
  const int lin = blockIdx.x;
  const int v = (lin & 7) * 128 + (lin >> 3);
  const int bh = v >> 4;
  const int qt = 15 - (v & 15);
  const int b = bh >> 4, h = bh & 15, kv = h >> 2;
  const int q0 = qt * 128;
  const int myrow = w * 16 + lg * 4;
  const size_t rowQ = (size_t)(b * T + q0 + w * 16 + lr) * CS + h * 128;
  bf16x8 qf[4];
#pragma unroll
  for (int di = 0; di < 4; ++di) qf[di] = *(const bf16x8*)&QKV[rowQ + di * 32 + lg * 8];
  bf16x8 onesf;
#pragma unroll
  for (int j = 0; j < 8; ++j) onesf[j] = (__bf16)1.0f;
  f32x4 lsum = {};
  f32x4 oacc[8] = {};
  const int lastst = 2 * qt + 1;
  const size_t kvBase = (size_t)(b * T) * CS + 2048 + kv * 128;
  const int sV = (t >> 4) * 2, d8V = (t & 15) * 8;
  u16x8 vr0, vr1;
  {
#pragma unroll
    for (int i = 0; i < 2; ++i) {
      int flat = t + i * 512;
      int r = flat >> 4, c = flat & 15;
      async16(&QKV[kvBase + (size_t)r * CS + ((c ^ (r & 7)) * 8)], &Ks[0][flat * 8]);
    }
    vr0 = *(const u16x8*)&QKV[kvBase + 512 + (size_t)sV * CS + d8V];
    vr1 = *(const u16x8*)&QKV[kvBase + 512 + (size_t)(sV + 1) * CS + d8V];
#pragma unroll
    for (int j = 0; j < 8; ++j) {
      int d = d8V + j;
      int slot = (sV >> 3) ^ ((d >> 3) & 7);
      *(unsigned*)&Vt[d * 72 + slot * 8 + (sV & 7)] = (unsigned)vr0[j] | ((unsigned)vr1[j] << 16);
    }
    __syncthreads();
  }
  int cb = 0;
  for (int st = 0; st <= lastst; ++st) {
    if (st < lastst) {
      const size_t kvRow = kvBase + (size_t)(st + 1) * 64 * CS;
#pragma unroll
      for (int i = 0; i < 2; ++i) {
        int flat = t + i * 512;
        int r = flat >> 4, c = flat & 15;
        async16(&QKV[kvRow + (size_t)r * CS + ((c ^ (r & 7)) * 8)], &Ks[cb ^ 1][flat * 8]);
      }
      vr0 = *(const u16x8*)&QKV[kvRow + 512 + (size_t)sV * CS + d8V];
      vr1 = *(const u16x8*)&QKV[kvRow + 512 + (size_t)(sV + 1) * CS + d8V];
    }
    const int s0 = st * 64;
    const bool skip = (st == lastst) && (w < 4);
    if (!skip) {
      f32x4 sacc[4] = {};
      __builtin_amdgcn_s_setprio(1);
#pragma unroll
      for (int di = 0; di < 4; ++di)
#pragma unroll
        for (int n = 0; n < 4; ++n) {
          bf16x8 bk =
              *(const bf16x8*)&Ks[cb][(n * 16 + lr) * 128 + (((di * 4 + lg) ^ (lr & 7)) << 3)];
          sacc[n] = MFMA16(qf[di], bk, sacc[n]);
        }
      __builtin_amdgcn_s_setprio(0);
      const bool diag = (st >= 2 * qt);
#pragma unroll
      for (int n = 0; n < 4; ++n)
#pragma unroll
        for (int r = 0; r < 4; ++r) {
          float s_ = sacc[n][r] * 1.44269504f - 11.5415603f;
          if (diag && (s0 + 16 * n + lr > q0 + myrow + r)) s_ = -1e30f;
          *(__bf16*)&Pl[(myrow + r) * 72 + 16 * n + lr] = (__bf16)exp2f(s_);
        }
      __builtin_amdgcn_s_setprio(1);
#pragma unroll
      for (int ks = 0; ks < 2; ++ks) {
        bf16x8 pa = *(const bf16x8*)&Pl[(w * 16 + lr) * 72 + ks * 32 + lg * 8];
        lsum = MFMA16(pa, onesf, lsum);
#pragma unroll
        for (int nf = 0; nf < 8; ++nf) {
          int d = 16 * nf + lr;
          int seg = lg + 4 * ks;
          bf16x8 vb = *(const bf16x8*)&Vt[d * 72 + ((seg ^ ((d >> 3) & 7)) << 3)];
          oacc[nf] = MFMA16(pa, vb, oacc[nf]);
        }
      }
      __builtin_amdgcn_s_setprio(0);
    }
    __syncthreads();
    if (st < lastst) {
#pragma unroll
      for (int j = 0; j < 8; ++j) {
        int d = d8V + j;
        int slot = (sV >> 3) ^ ((d >> 3) & 7);
        *(unsigned*)&Vt[d * 72 + slot * 8 + (sV & 7)] =
            (unsigned)vr0[j] | ((unsigned)vr1[j] << 16);
      }
    }
    __syncthreads();
    cb ^= 1;
  }
#pragma unroll
  for (int r = 0; r < 4; ++r) {
    float il = 1.0f / lsum[r];
    size_t orow = (size_t)(b * T + q0 + myrow + r) * OC + h * 128;
#pragma unroll
    for (int nf = 0; nf < 8; ++nf) O[orow + 16 * nf + lr] = f2bf(oacc[nf][r] * il);
  }
}

// ---------------- ws-too-small sentinel (distinguishable failure) ----------------
__global__ __launch_bounds__(256) void sentinel_k(float* __restrict__ out) {
  out[blockIdx.x * 256 + threadIdx.x] = 1.0e4f;
}

extern "C" void kernel_launch(void* const* d_in, const int* in_sizes, int n_in, void* d_out,
                              int out_size, void* d_ws, size_t ws_size, hipStream_t stream) {
  const float* x = (const float*)d_in[0];
  const float* Wq = (const float*)d_in[1];
  const float* Wk = (const float*)d_in[2];
  const float* Wv = (const float*)d_in[3];
  const float* Wo = (const float*)d_in[4];

  char* p = (char*)d_ws;
  auto take = [&](size_t bytes) {
    char* r = p;
    p += (bytes + 255) & ~(size_t)255;
    return r;
  };
  u16* WqkvT = (u16*)take((size_t)3072 * 2048 * 2);  // [3072][2048] = [Wq^T; Wk^T; Wv^T]
  u16* WoT = (u16*)take((size_t)2048 * 2048 * 2);
  u16* QKV = (u16*)take((size_t)8192 * 3072 * 2);
  u16* Ob = (u16*)take((size_t)8192 * 2048 * 2);
  u16* xbf = (u16*)take((size_t)8192 * 2048 * 2);
  float* cosT = (float*)take((size_t)2048 * 64 * 4);
  float* sinT = (float*)take((size_t)2048 * 64 * 4);
  if (ws_size < (size_t)(p - (char*)d_ws)) {
    sentinel_k<<<4, 256, 0, stream>>>((float*)d_out);
    return;
  }

  convert_k<<<2048, 256, 0, stream>>>(x, xbf, 8192 * 2048 / 8);
  transpose_cvt_k<<<dim3(32, 32), 256, 0, stream>>>(Wq, WqkvT, 2048, 2048);
  transpose_cvt_k<<<dim3(8, 32), 256, 0, stream>>>(Wk, WqkvT + (size_t)2048 * 2048, 2048, 512);
  transpose_cvt_k<<<dim3(8, 32), 256, 0, stream>>>(Wv, WqkvT + (size_t)2560 * 2048, 2048, 512);
  transpose_cvt_k<<<dim3(32, 32), 256, 0, stream>>>(Wo, WoT, 2048, 2048);
  rope_table_k<<<512, 256, 0, stream>>>(cosT, sinT);

  // QKV projection: [8192,2048] @ [2048,3072] -> bf16 (8-phase 256^2, grid 12x32=384)
  gemm8p<false><<<dim3(12, 32), 512, 0, stream>>>(xbf, WqkvT, QKV, 8192, 3072, 2048);

  // RoPE (scale 1/sqrt(128) folded into Q)
  rope_apply_k<<<8192, 256, 0, stream>>>(QKV, cosT, sinT, 3072, 15, 8, 0.08838834764831845f);
  rope_apply_k<<<2048, 256, 0, stream>>>(QKV + 2048, cosT, sinT, 3072, 3, 6, 1.0f);

  // causal GQA attention (1024 blocks x 512 threads, XCD-chunked internally)
  attn_k<<<1024, 512, 0, stream>>>(QKV, Ob);

  // output projection: [8192,2048] @ [2048,2048] -> fp32 (8-phase 256^2, grid 8x32=256)
  gemm8p<true><<<dim3(8, 32), 512, 0, stream>>>(Ob, WoT, (void*)d_out, 8192, 2048, 2048);
}

// Round 14
// 462.800 us; speedup vs baseline: 1.0313x; 1.0313x over previous
//
#include <hip/hip_runtime.h>

typedef unsigned short u16;
typedef __bf16 bf16x8 __attribute__((ext_vector_type(8)));
typedef u16 u16x8 __attribute__((ext_vector_type(8)));
typedef u16 u16x4 __attribute__((ext_vector_type(4)));
typedef float f32x4 __attribute__((ext_vector_type(4)));

#define MFMA16(a, b, c) __builtin_amdgcn_mfma_f32_16x16x32_bf16((a), (b), (c), 0, 0, 0)

__device__ __forceinline__ void async16(const u16* g, u16* l) {
  __builtin_amdgcn_global_load_lds(
      (__attribute__((address_space(1))) void*)(void*)(g),
      (__attribute__((address_space(3))) void*)(void*)(l), 16, 0, 0);
}

__device__ __forceinline__ float bf2f(u16 b) {
  union { unsigned u; float f; } v;
  v.u = ((unsigned)b) << 16;
  return v.f;
}
__device__ __forceinline__ u16 f2bf(float f) {
  union { float f; unsigned u; } v;
  v.f = f;
  unsigned u = v.u;
  return (u16)((u + 0x7FFFu + ((u >> 16) & 1u)) >> 16);
}

// ---------------- input convert: fp32 -> bf16, 8 elems/thread ----------------
__global__ __launch_bounds__(256) void convert_k(const float* __restrict__ in,
                                                 u16* __restrict__ out, int n8) {
  const int stride = gridDim.x * 256;
  for (int i = blockIdx.x * 256 + threadIdx.x; i < n8; i += stride) {
    const float* fp = in + (size_t)i * 8;
    float4 a = *(const float4*)fp, b = *(const float4*)(fp + 4);
    u16x8 o;
    o[0] = f2bf(a.x); o[1] = f2bf(a.y); o[2] = f2bf(a.z); o[3] = f2bf(a.w);
    o[4] = f2bf(b.x); o[5] = f2bf(b.y); o[6] = f2bf(b.z); o[7] = f2bf(b.w);
    *(u16x8*)&out[(size_t)i * 8] = o;
  }
}

// ---------------- weight transpose+convert: W[K][N] fp32 -> Wt[N][K] bf16 ----------------
__global__ __launch_bounds__(256) void transpose_cvt_k(const float* __restrict__ W,
                                                       u16* __restrict__ Wt, int K, int N) {
  __shared__ __align__(16) u16 tile[64 * 72];
  const int t = threadIdx.x;
  const int n0 = blockIdx.x * 64, k0 = blockIdx.y * 64;
#pragma unroll
  for (int i = 0; i < 2; ++i) {
    int flat = t + i * 256;
    int r = flat >> 3, c8 = (flat & 7) * 8;
    const float* p = W + (size_t)(k0 + r) * N + n0 + c8;
    float4 a = *(const float4*)p, b = *(const float4*)(p + 4);
    u16x8 v;
    v[0] = f2bf(a.x); v[1] = f2bf(a.y); v[2] = f2bf(a.z); v[3] = f2bf(a.w);
    v[4] = f2bf(b.x); v[5] = f2bf(b.y); v[6] = f2bf(b.z); v[7] = f2bf(b.w);
#pragma unroll
    for (int j = 0; j < 8; ++j) tile[r * 72 + c8 + j] = v[j];
  }
  __syncthreads();
#pragma unroll
  for (int i = 0; i < 2; ++i) {
    int flat = t + i * 256;
    int r = flat >> 3, c8 = (flat & 7) * 8;
    u16x8 v;
#pragma unroll
    for (int j = 0; j < 8; ++j) v[j] = tile[(c8 + j) * 72 + r];
    *(u16x8*)&Wt[(size_t)(n0 + r) * K + k0 + c8] = v;
  }
}

// ---------------- RoPE cos/sin table: [2048][64] f32 ----------------
__global__ __launch_bounds__(256) void rope_table_k(float* __restrict__ cosT,
                                                    float* __restrict__ sinT) {
  int idx = blockIdx.x * 256 + threadIdx.x;  // t*64 + i
  int tp = idx >> 6, i = idx & 63;
  float invf = expf(-(float)i * (9.210340371976184f / 64.0f));  // 10000^{-i/64}
  float ang = (float)tp * invf;
  cosT[idx] = cosf(ang);
  sinT[idx] = sinf(ang);
}

// ---------------- RoPE apply (in place), optional scale fold ----------------
__global__ __launch_bounds__(256) void rope_apply_k(u16* __restrict__ base,
                                                    const float* __restrict__ cosT,
                                                    const float* __restrict__ sinT,
                                                    int rowStride, int nhMask, int rowShift,
                                                    float scale) {
  int idx = blockIdx.x * 256 + threadIdx.x;
  int i4 = idx & 15;
  int hh = (idx >> 4) & nhMask;
  int row = idx >> rowShift;
  int tp = row & 2047;
  int i = i4 * 4;
  u16* p = base + (size_t)row * rowStride + hh * 128;
  u16x4 a = *(u16x4*)&p[i];
  u16x4 b = *(u16x4*)&p[i + 64];
  float4 c = *(const float4*)&cosT[tp * 64 + i];
  float4 s = *(const float4*)&sinT[tp * 64 + i];
  float cc[4] = {c.x, c.y, c.z, c.w}, ss[4] = {s.x, s.y, s.z, s.w};
  u16x4 oa, ob;
#pragma unroll
  for (int j = 0; j < 4; ++j) {
    float x1 = bf2f(a[j]), x2 = bf2f(b[j]);
    oa[j] = f2bf((x1 * cc[j] - x2 * ss[j]) * scale);
    ob[j] = f2bf((x2 * cc[j] + x1 * ss[j]) * scale);
  }
  *(u16x4*)&p[i] = oa;
  *(u16x4*)&p[i + 64] = ob;
}

// ---------------- GEMM: C[M][N] = A[M][K] @ Bt[N][K]^T  (m97 structure + XCD swizzle) ----------------
// Kept over the r13 8-phase port: coarse phase-split without deep interleave was neutral (m196).
template <bool F32OUT>
__global__ __launch_bounds__(256) void gemm_tn(const u16* __restrict__ A,
                                               const u16* __restrict__ Bt,
                                               void* __restrict__ C, int M, int N, int K) {
  __shared__ __align__(16) u16 As[128 * 32];
  __shared__ __align__(16) u16 Bs[128 * 32];
  const int t = threadIdx.x;
  const int l = t & 63, w = t >> 6;
  const int wm = w >> 1, wn = w & 1;
  const int lr = l & 15, lg = l >> 4;
  const int nbx = gridDim.x;
  const int lin = blockIdx.y * nbx + blockIdx.x;
  const int cpx = (nbx * gridDim.y) >> 3;
  const int sl = (lin & 7) * cpx + (lin >> 3);
  const size_t m0 = (size_t)(sl / nbx) * 128, n0 = (size_t)(sl % nbx) * 128;
  f32x4 acc[4][4] = {};
  for (int k0 = 0; k0 < K; k0 += 32) {
#pragma unroll
    for (int i = 0; i < 2; ++i) {
      int flat = t + i * 256;
      int r = flat >> 2, seg = (flat & 3) * 8;
      async16(&A[(m0 + r) * K + k0 + seg], &As[flat * 8]);
      async16(&Bt[(n0 + r) * K + k0 + seg], &Bs[flat * 8]);
    }
    __syncthreads();
    bf16x8 af[4], bfr[4];
#pragma unroll
    for (int i = 0; i < 4; ++i) {
      af[i] = *(const bf16x8*)&As[(wm * 64 + i * 16 + lr) * 32 + lg * 8];
      bfr[i] = *(const bf16x8*)&Bs[(wn * 64 + i * 16 + lr) * 32 + lg * 8];
    }
#pragma unroll
    for (int mi = 0; mi < 4; ++mi)
#pragma unroll
      for (int ni = 0; ni < 4; ++ni) acc[mi][ni] = MFMA16(af[mi], bfr[ni], acc[mi][ni]);
    __syncthreads();
  }
#pragma unroll
  for (int mi = 0; mi < 4; ++mi)
#pragma unroll
    for (int ni = 0; ni < 4; ++ni)
#pragma unroll
      for (int r = 0; r < 4; ++r) {
        size_t row = m0 + wm * 64 + mi * 16 + lg * 4 + r;
        size_t col = n0 + wn * 64 + ni * 16 + lr;
        if constexpr (F32OUT)
          ((float*)C)[row * N + col] = acc[mi][ni][r];
        else
          ((u16*)C)[row * N + col] = f2bf(acc[mi][ni][r]);
      }
}

// ---------------- causal GQA flash attention (8-wave, QBLK=128, 16x16 MFMA, 2-phase) ----------------
// Round-8 configuration — best measured (190 us; session total 460.4). P = exp(S-8) const-shift
// softmax, row-sum via MFMA vs ones; K dbuf via global_load_lds; V reg-prefetch write-late.
// Bracketing results: QBLK=64 192us (r5) | this 190us (r8) | +setprio +5us (r12) | 32x32 220us (r11).
// Toolchain note: __launch_bounds__(512,N) empirically caps VGPR at ~256/N; this kernel fits in 64.
__global__ __launch_bounds__(512, 4) void attn_k(const u16* __restrict__ QKV,
                                                 u16* __restrict__ O) {
  constexpr int T = 2048, CS = 3072, OC = 2048;
  __shared__ __align__(16) u16 Ks[2][64 * 128];  // chunk-swizzled: chunk c of row r = global c^(r&7)
  __shared__ __align__(16) u16 Vt[128 * 72];     // [d][72], slot=(s>>3)^((d>>3)&7)
  __shared__ __align__(16) u16 Pl[128 * 72];     // P rows (per-wave private rows)
  const int t = threadIdx.x, l = t & 63, w = t >> 6, lr = l & 15, lg = l >> 4;
  const int lin = blockIdx.x;
  const int v = (lin & 7) * 128 + (lin >> 3);
  const int bh = v >> 4;
  const int qt = 15 - (v & 15);
  const int b = bh >> 4, h = bh & 15, kv = h >> 2;
  const int q0 = qt * 128;
  const int myrow = w * 16 + lg * 4;
  const size_t rowQ = (size_t)(b * T + q0 + w * 16 + lr) * CS + h * 128;
  bf16x8 qf[4];
#pragma unroll
  for (int di = 0; di < 4; ++di) qf[di] = *(const bf16x8*)&QKV[rowQ + di * 32 + lg * 8];
  bf16x8 onesf;
#pragma unroll
  for (int j = 0; j < 8; ++j) onesf[j] = (__bf16)1.0f;
  f32x4 lsum = {};
  f32x4 oacc[8] = {};
  const int lastst = 2 * qt + 1;
  const size_t kvBase = (size_t)(b * T) * CS + 2048 + kv * 128;
  const int sV = (t >> 4) * 2, d8V = (t & 15) * 8;
  u16x8 vr0, vr1;
  // ---- prologue: stage tile 0 (K -> Ks[0], V -> regs -> Vt) ----
  {
#pragma unroll
    for (int i = 0; i < 2; ++i) {
      int flat = t + i * 512;
      int r = flat >> 4, c = flat & 15;
      async16(&QKV[kvBase + (size_t)r * CS + ((c ^ (r & 7)) * 8)], &Ks[0][flat * 8]);
    }
    vr0 = *(const u16x8*)&QKV[kvBase + 512 + (size_t)sV * CS + d8V];
    vr1 = *(const u16x8*)&QKV[kvBase + 512 + (size_t)(sV + 1) * CS + d8V];
#pragma unroll
    for (int j = 0; j < 8; ++j) {
      int d = d8V + j;
      int slot = (sV >> 3) ^ ((d >> 3) & 7);
      *(unsigned*)&Vt[d * 72 + slot * 8 + (sV & 7)] =
          (unsigned)vr0[j] | ((unsigned)vr1[j] << 16);
    }
    __syncthreads();  // drains K(0) gload_lds; publishes Vt(0)
  }
  int cb = 0;
  for (int st = 0; st <= lastst; ++st) {
    // ---- issue next-tile loads (latency hides under this stage's compute) ----
    if (st < lastst) {
      const size_t kvRow = kvBase + (size_t)(st + 1) * 64 * CS;
#pragma unroll
      for (int i = 0; i < 2; ++i) {
        int flat = t + i * 512;
        int r = flat >> 4, c = flat & 15;
        async16(&QKV[kvRow + (size_t)r * CS + ((c ^ (r & 7)) * 8)], &Ks[cb ^ 1][flat * 8]);
      }
      vr0 = *(const u16x8*)&QKV[kvRow + 512 + (size_t)sV * CS + d8V];
      vr1 = *(const u16x8*)&QKV[kvRow + 512 + (size_t)(sV + 1) * CS + d8V];
    }
    // ---- compute on current buffers ----
    const int s0 = st * 64;
    const bool skip = (st == lastst) && (w < 4);  // fully-masked waves on last tile
    if (!skip) {
      f32x4 sacc[4] = {};
#pragma unroll
      for (int di = 0; di < 4; ++di)
#pragma unroll
        for (int n = 0; n < 4; ++n) {
          bf16x8 bk =
              *(const bf16x8*)&Ks[cb][(n * 16 + lr) * 128 + (((di * 4 + lg) ^ (lr & 7)) << 3)];
          sacc[n] = MFMA16(qf[di], bk, sacc[n]);
        }
      const bool diag = (st >= 2 * qt);
#pragma unroll
      for (int n = 0; n < 4; ++n)
#pragma unroll
        for (int r = 0; r < 4; ++r) {
          float s_ = sacc[n][r] * 1.44269504f - 11.5415603f;
          if (diag && (s0 + 16 * n + lr > q0 + myrow + r)) s_ = -1e30f;
          *(__bf16*)&Pl[(myrow + r) * 72 + 16 * n + lr] = (__bf16)exp2f(s_);
        }
#pragma unroll
      for (int ks = 0; ks < 2; ++ks) {
        bf16x8 pa = *(const bf16x8*)&Pl[(w * 16 + lr) * 72 + ks * 32 + lg * 8];
        lsum = MFMA16(pa, onesf, lsum);
#pragma unroll
        for (int nf = 0; nf < 8; ++nf) {
          int d = 16 * nf + lr;
          int seg = lg + 4 * ks;
          bf16x8 vb = *(const bf16x8*)&Vt[d * 72 + ((seg ^ ((d >> 3) & 7)) << 3)];
          oacc[nf] = MFMA16(pa, vb, oacc[nf]);
        }
      }
    }
    __syncthreads();  // PV reads of Vt done; drains vmcnt: K(st+1) in Ks, V regs ready
    if (st < lastst) {
#pragma unroll
      for (int j = 0; j < 8; ++j) {
        int d = d8V + j;
        int slot = (sV >> 3) ^ ((d >> 3) & 7);
        *(unsigned*)&Vt[d * 72 + slot * 8 + (sV & 7)] =
            (unsigned)vr0[j] | ((unsigned)vr1[j] << 16);
      }
    }
    __syncthreads();  // Vt(st+1) published
    cb ^= 1;
  }
#pragma unroll
  for (int r = 0; r < 4; ++r) {
    float il = 1.0f / lsum[r];
    size_t orow = (size_t)(b * T + q0 + myrow + r) * OC + h * 128;
#pragma unroll
    for (int nf = 0; nf < 8; ++nf) O[orow + 16 * nf + lr] = f2bf(oacc[nf][r] * il);
  }
}

// ---------------- ws-too-small sentinel (distinguishable failure) ----------------
__global__ __launch_bounds__(256) void sentinel_k(float* __restrict__ out) {
  out[blockIdx.x * 256 + threadIdx.x] = 1.0e4f;
}

extern "C" void kernel_launch(void* const* d_in, const int* in_sizes, int n_in, void* d_out,
                              int out_size, void* d_ws, size_t ws_size, hipStream_t stream) {
  const float* x = (const float*)d_in[0];
  const float* Wq = (const float*)d_in[1];
  const float* Wk = (const float*)d_in[2];
  const float* Wv = (const float*)d_in[3];
  const float* Wo = (const float*)d_in[4];

  char* p = (char*)d_ws;
  auto take = [&](size_t bytes) {
    char* r = p;
    p += (bytes + 255) & ~(size_t)255;
    return r;
  };
  u16* WqkvT = (u16*)take((size_t)3072 * 2048 * 2);  // [3072][2048] = [Wq^T; Wk^T; Wv^T]
  u16* WoT = (u16*)take((size_t)2048 * 2048 * 2);
  u16* QKV = (u16*)take((size_t)8192 * 3072 * 2);
  u16* Ob = (u16*)take((size_t)8192 * 2048 * 2);
  u16* xbf = (u16*)take((size_t)8192 * 2048 * 2);
  float* cosT = (float*)take((size_t)2048 * 64 * 4);
  float* sinT = (float*)take((size_t)2048 * 64 * 4);
  if (ws_size < (size_t)(p - (char*)d_ws)) {
    sentinel_k<<<4, 256, 0, stream>>>((float*)d_out);
    return;
  }

  convert_k<<<2048, 256, 0, stream>>>(x, xbf, 8192 * 2048 / 8);
  transpose_cvt_k<<<dim3(32, 32), 256, 0, stream>>>(Wq, WqkvT, 2048, 2048);
  transpose_cvt_k<<<dim3(8, 32), 256, 0, stream>>>(Wk, WqkvT + (size_t)2048 * 2048, 2048, 512);
  transpose_cvt_k<<<dim3(8, 32), 256, 0, stream>>>(Wv, WqkvT + (size_t)2560 * 2048, 2048, 512);
  transpose_cvt_k<<<dim3(32, 32), 256, 0, stream>>>(Wo, WoT, 2048, 2048);
  rope_table_k<<<512, 256, 0, stream>>>(cosT, sinT);

  // QKV projection: [8192,2048] @ [2048,3072] -> bf16
  gemm_tn<false><<<dim3(24, 64), 256, 0, stream>>>(xbf, WqkvT, QKV, 8192, 3072, 2048);

  // RoPE (scale 1/sqrt(128) folded into Q)
  rope_apply_k<<<8192, 256, 0, stream>>>(QKV, cosT, sinT, 3072, 15, 8, 0.08838834764831845f);
  rope_apply_k<<<2048, 256, 0, stream>>>(QKV + 2048, cosT, sinT, 3072, 3, 6, 1.0f);

  // causal GQA attention (1024 blocks x 512 threads, XCD-chunked internally)
  attn_k<<<1024, 512, 0, stream>>>(QKV, Ob);

  // output projection: [8192,2048] @ [2048,2048] -> fp32 (reference output dtype)
  gemm_tn<true><<<dim3(16, 64), 256, 0, stream>>>(Ob, WoT, (void*)d_out, 8192, 2048, 2048);
}